// Round 2
// baseline (76.735 us; speedup 1.0000x reference)
//
#include <hip/hip_runtime.h>

#define B_SZ 2048
#define F_SZ 24
#define E_SZ 128
#define P_SZ 276           // F*(F-1)/2
#define BT   128           // batch rows per block
#define NB   (B_SZ / BT)   // 16
#define NWG  (P_SZ * NB)   // 4416 = 8 * 552 (bijective XCD remap ok)

typedef __bf16 bf16x8 __attribute__((ext_vector_type(8)));
typedef float  f32x16 __attribute__((ext_vector_type(16)));

__global__ __launch_bounds__(512, 4) void opn_pairwise_kernel(
    const float* __restrict__ x,      // [B, F, E]
    const float* __restrict__ kern,   // [E(d), P, E(e)]
    float* __restrict__ out)          // [B, P]
{
    // bf16 tiles, XOR-swizzled at 16B granularity with (row & 15)
    __shared__ short sA[BT * E_SZ];     // Xp tile  (128 x 128) 32 KB
    __shared__ short sB[E_SZ * E_SZ];   // K_p tile (128 x 128) 32 KB
    __shared__ float red[2][BT];        // cross-wave d-half reduce, 1 KB

    const int tid = threadIdx.x;

    // XCD-grouped bijective remap: each XCD gets a contiguous wgid range,
    // so one pair's 16 batch-blocks share that XCD's L2 copy of K_p.
    const int orig = blockIdx.x;
    const int wgid = (orig & 7) * (NWG / 8) + (orig >> 3);
    const int p  = wgid >> 4;           // wgid / NB
    const int bb = wgid & 15;
    const int b0 = bb * BT;

    // p -> (fp, fq) for triu_indices(F, k=1)
    int fp = 0, rem = p;
    while (rem >= F_SZ - 1 - fp) { rem -= F_SZ - 1 - fp; ++fp; }
    const int fq = fp + 1 + rem;

    // ---- stage Xp: 128 rows x 128 e, fp32 -> bf16, 16B writes, swizzled ----
#pragma unroll
    for (int k = 0; k < 4; ++k) {
        int i = tid + k * 512;          // 16B-slot id: 0..2047
        int r = i >> 4, s8 = i & 15;
        const float* src = x + ((size_t)(b0 + r) * F_SZ + fp) * E_SZ + s8 * 8;
        float4 v0 = *(const float4*)src;
        float4 v1 = *(const float4*)(src + 4);
        bf16x8 h;
        h[0] = (__bf16)v0.x; h[1] = (__bf16)v0.y; h[2] = (__bf16)v0.z; h[3] = (__bf16)v0.w;
        h[4] = (__bf16)v1.x; h[5] = (__bf16)v1.y; h[6] = (__bf16)v1.z; h[7] = (__bf16)v1.w;
        *(bf16x8*)&sA[r * E_SZ + ((s8 ^ (r & 15)) << 3)] = h;
    }
    // ---- stage K_p: 128 rows(d) x 128 e, row stride P*E in global ----
#pragma unroll
    for (int k = 0; k < 4; ++k) {
        int i = tid + k * 512;
        int r = i >> 4, s8 = i & 15;
        const float* src = kern + ((size_t)r * P_SZ + p) * E_SZ + s8 * 8;
        float4 v0 = *(const float4*)src;
        float4 v1 = *(const float4*)(src + 4);
        bf16x8 h;
        h[0] = (__bf16)v0.x; h[1] = (__bf16)v0.y; h[2] = (__bf16)v0.z; h[3] = (__bf16)v0.w;
        h[4] = (__bf16)v1.x; h[5] = (__bf16)v1.y; h[6] = (__bf16)v1.z; h[7] = (__bf16)v1.w;
        *(bf16x8*)&sB[r * E_SZ + ((s8 ^ (r & 15)) << 3)] = h;
    }
    __syncthreads();

    const int w    = tid >> 6;          // wave 0..7
    const int lane = tid & 63;
    const int l31  = lane & 31;
    const int hi   = lane >> 5;
    const int mh   = w >> 2;            // d-half (rows mh*64 .. +63)
    const int ng   = w & 3;             // batch group of 32 (cols ng*32 .. +31)

    // ---- MFMA: T[d, b] = K_p[d,e] . Xp[b,e]^T  (A = K_p, B = Xp^T) ----
    // 32x32x16: a/b-frag lane&31 = row/col, k = (lane>>5)*8 + i
    f32x16 acc[2];
#pragma unroll
    for (int mt = 0; mt < 2; ++mt)
#pragma unroll
        for (int j = 0; j < 16; ++j) acc[mt][j] = 0.f;

    const int brow = ng * 32 + l31;     // this lane's batch column b (local)
    const int bswz = brow * E_SZ;
#pragma unroll
    for (int kk = 0; kk < 8; ++kk) {
        const int e8 = kk * 2 + hi;     // 16B-slot along e
        bf16x8 bfr = *(const bf16x8*)&sA[bswz + ((e8 ^ (brow & 15)) << 3)];
#pragma unroll
        for (int mt = 0; mt < 2; ++mt) {
            int arow = (mh * 2 + mt) * 32 + l31;   // d row
            bf16x8 afr = *(const bf16x8*)&sB[arow * E_SZ + ((e8 ^ (arow & 15)) << 3)];
            acc[mt] = __builtin_amdgcn_mfma_f32_32x32x16_bf16(afr, bfr, acc[mt], 0, 0, 0);
        }
    }

    // ---- epilogue: s[b] = sum_d T[d,b] * Xq[b,d] ----
    // D layout: col = lane&31 (= b), row = (reg&3) + 8*(reg>>2) + 4*hi
    const float* xqp = x + ((size_t)(b0 + brow) * F_SZ + fq) * E_SZ;
    float s = 0.f;
#pragma unroll
    for (int mt = 0; mt < 2; ++mt) {
        const int dbase = (mh * 2 + mt) * 32 + hi * 4;
#pragma unroll
        for (int q = 0; q < 4; ++q) {
            float4 xq = *(const float4*)(xqp + dbase + q * 8);
            s += acc[mt][q * 4 + 0] * xq.x + acc[mt][q * 4 + 1] * xq.y
               + acc[mt][q * 4 + 2] * xq.z + acc[mt][q * 4 + 3] * xq.w;
        }
    }
    s += __shfl_xor(s, 32);             // combine the two hi k/row groups
    if (hi == 0) red[mh][brow] = s;     // per d-half partial for batch col b
    __syncthreads();

    if (tid < BT)
        out[(size_t)(b0 + tid) * P_SZ + p] = red[0][tid] + red[1][tid];
}

extern "C" void kernel_launch(void* const* d_in, const int* in_sizes, int n_in,
                              void* d_out, int out_size, void* d_ws, size_t ws_size,
                              hipStream_t stream) {
    const float* x    = (const float*)d_in[0];   // [2048, 24, 128] f32
    const float* kern = (const float*)d_in[1];   // [128, 276, 128] f32
    float* out = (float*)d_out;                  // [2048, 276] f32
    opn_pairwise_kernel<<<dim3(NWG), 512, 0, stream>>>(x, kern, out);
}